// Round 1
// baseline (316.475 us; speedup 1.0000x reference)
//
#include <hip/hip_runtime.h>
#include <math.h>

#define NB 256     // batch
#define IC 1152    // input capsules
#define OC 10      // output capsules
#define OU 16      // output units
#define IK 8       // input units

// ---------------- softmax over o for each input capsule i ----------------
__global__ void softmax_kernel(const float* __restrict__ blog, float* __restrict__ c) {
    int i = blockIdx.x * blockDim.x + threadIdx.x;
    if (i >= IC) return;
    float x[OC];
    float m = -1e30f;
#pragma unroll
    for (int o = 0; o < OC; ++o) { x[o] = blog[i * OC + o]; m = fmaxf(m, x[o]); }
    float sum = 0.f;
#pragma unroll
    for (int o = 0; o < OC; ++o) { x[o] = expf(x[o] - m); sum += x[o]; }
    float inv = 1.f / sum;
#pragma unroll
    for (int o = 0; o < OC; ++o) c[i * OC + o] = x[o] * inv;
}

// ---------------- s-pass: s[b,o,u] = sum_i c[i,o]*dot8(W[i,o,u,:], inp[b,i,:])
//                  fused squash -> v (written to d_out) ----------------
// block: (o, batch-tile of 8). 512 threads = 8 u-pairs x 64 i-slots.
#define S_BB 8
#define S_ICH 64
__global__ __launch_bounds__(512) void spass_kernel(
    const float* __restrict__ inp,   // [NB][IC][IK]
    const float* __restrict__ W,     // [IC][OC][OU][IK]
    const float* __restrict__ c,     // [IC][OC]
    float* __restrict__ vout)        // [NB][OC][OU]
{
    const int o   = blockIdx.x;
    const int b0  = blockIdx.y * S_BB;
    const int tid = threadIdx.x;
    const int up  = tid & 7;     // u-pair: u = up and up+8
    const int is  = tid >> 3;    // 0..63, i within chunk

    // stride 12 floats per i-row: 48B (16B-aligned), distinct bank-quads per is
    __shared__ float inl[S_BB][S_ICH * 12];       // 24 KB
    __shared__ float sred[S_ICH][S_BB][OU];       // 32 KB

    float acc0[S_BB], acc1[S_BB];
#pragma unroll
    for (int bl = 0; bl < S_BB; ++bl) { acc0[bl] = 0.f; acc1[bl] = 0.f; }

    for (int i0 = 0; i0 < IC; i0 += S_ICH) {
        __syncthreads();
        // stage inp[b0..b0+7][i0..i0+63][0..7] : 4096 floats = 1024 float4
#pragma unroll
        for (int j = 0; j < 2; ++j) {
            int q   = tid + j * 512;    // float4 id
            int bl  = q >> 7;           // 128 float4 per b-row
            int rem = q & 127;
            int iis = rem >> 1;
            int kk  = (rem & 1) * 4;
            float4 g = *(const float4*)&inp[(size_t)(b0 + bl) * (IC * IK) +
                                            (size_t)(i0 + iis) * IK + kk];
            *(float4*)&inl[bl][iis * 12 + kk] = g;
        }
        __syncthreads();

        // W fragment for (i0+is, o, up / up+8) straight from global (L2-hot)
        const float* wrow = &W[((size_t)(i0 + is) * OC + o) * (OU * IK)];
        float4 w0a = *(const float4*)(wrow + up * 8);
        float4 w0b = *(const float4*)(wrow + up * 8 + 4);
        float4 w1a = *(const float4*)(wrow + (up + 8) * 8);
        float4 w1b = *(const float4*)(wrow + (up + 8) * 8 + 4);
        float cc   = c[(size_t)(i0 + is) * OC + o];

#pragma unroll
        for (int bl = 0; bl < S_BB; ++bl) {
            float4 xa = *(const float4*)&inl[bl][is * 12];
            float4 xb = *(const float4*)&inl[bl][is * 12 + 4];
            float d0 = w0a.x * xa.x + w0a.y * xa.y + w0a.z * xa.z + w0a.w * xa.w
                     + w0b.x * xb.x + w0b.y * xb.y + w0b.z * xb.z + w0b.w * xb.w;
            float d1 = w1a.x * xa.x + w1a.y * xa.y + w1a.z * xa.z + w1a.w * xa.w
                     + w1b.x * xb.x + w1b.y * xb.y + w1b.z * xb.z + w1b.w * xb.w;
            acc0[bl] += cc * d0;
            acc1[bl] += cc * d1;
        }
    }

    __syncthreads();
#pragma unroll
    for (int bl = 0; bl < S_BB; ++bl) {
        sred[is][bl][up]     = acc0[bl];
        sred[is][bl][up + 8] = acc1[bl];
    }
    __syncthreads();

    if (tid < S_BB * OU) {
        int bl = tid >> 4, u = tid & 15;
        float s = 0.f;
        for (int j = 0; j < S_ICH; ++j) s += sred[j][bl][u];
        // squash over the 16 u's of this (b,o): lanes bl*16+u are contiguous
        float sq = s * s;
        sq += __shfl_xor(sq, 1);
        sq += __shfl_xor(sq, 2);
        sq += __shfl_xor(sq, 4);
        sq += __shfl_xor(sq, 8);
        float vv = s * (sq / ((1.f + sq) * sqrtf(sq + 1e-9f)));
        vout[((size_t)(b0 + bl) * OC + o) * OU + u] = vv;
    }
}

// ---------------- delta-pass: b[i,o] += (1/NB) * sum_{b,u} uhat[b,i,o,u]*v[b,o,u]
// block: (o, i-tile of 32). 256 threads = 8 u-pairs x 32 i's.
#define D_BB 16
__global__ __launch_bounds__(256) void delta_kernel(
    const float* __restrict__ inp,   // [NB][IC][IK]
    const float* __restrict__ W,     // [IC][OC][OU][IK]
    const float* __restrict__ v,     // [NB][OC][OU]  (== d_out)
    float* __restrict__ blog)        // [IC][OC], updated in place
{
    const int o   = blockIdx.x;
    const int i0  = blockIdx.y * 32;
    const int tid = threadIdx.x;
    const int up  = tid & 7;     // u-pair {up, up+8}
    const int is  = tid >> 3;    // 0..31

    __shared__ float vl[NB][OU];          // 16 KB, staged once
    __shared__ float inl[D_BB][32 * 12];  // 24 KB
    __shared__ float dred[32][8];

    // stage v[:, o, :] : 4096 floats = 1024 float4
#pragma unroll
    for (int j = 0; j < 4; ++j) {
        int q  = tid + j * 256;
        int bb = q >> 2, rem = q & 3;
        *(float4*)&vl[bb][rem * 4] =
            *(const float4*)&v[((size_t)bb * OC + o) * OU + rem * 4];
    }

    const float* wrow = &W[((size_t)(i0 + is) * OC + o) * (OU * IK)];
    float4 w0a = *(const float4*)(wrow + up * 8);
    float4 w0b = *(const float4*)(wrow + up * 8 + 4);
    float4 w1a = *(const float4*)(wrow + (up + 8) * 8);
    float4 w1b = *(const float4*)(wrow + (up + 8) * 8 + 4);

    float acc = 0.f;
    for (int b0 = 0; b0 < NB; b0 += D_BB) {
        __syncthreads();
#pragma unroll
        for (int j = 0; j < 4; ++j) {
            int q   = tid + j * 256;
            int bl  = q >> 6, rem = q & 63;   // 64 float4 per b-row (256 floats)
            int iis = rem >> 1, kk = (rem & 1) * 4;
            *(float4*)&inl[bl][iis * 12 + kk] =
                *(const float4*)&inp[(size_t)(b0 + bl) * (IC * IK) +
                                     (size_t)(i0 + iis) * IK + kk];
        }
        __syncthreads();
#pragma unroll
        for (int bl = 0; bl < D_BB; ++bl) {
            float4 xa = *(const float4*)&inl[bl][is * 12];
            float4 xb = *(const float4*)&inl[bl][is * 12 + 4];
            float d0 = w0a.x * xa.x + w0a.y * xa.y + w0a.z * xa.z + w0a.w * xa.w
                     + w0b.x * xb.x + w0b.y * xb.y + w0b.z * xb.z + w0b.w * xb.w;
            float d1 = w1a.x * xa.x + w1a.y * xa.y + w1a.z * xa.z + w1a.w * xa.w
                     + w1b.x * xb.x + w1b.y * xb.y + w1b.z * xb.z + w1b.w * xb.w;
            acc += d0 * vl[b0 + bl][up] + d1 * vl[b0 + bl][up + 8];
        }
    }
    dred[is][up] = acc;
    __syncthreads();
    if (tid < 32) {
        float s = 0.f;
#pragma unroll
        for (int j = 0; j < 8; ++j) s += dred[tid][j];
        blog[(size_t)(i0 + tid) * OC + o] += s * (1.0f / NB);
    }
}

extern "C" void kernel_launch(void* const* d_in, const int* in_sizes, int n_in,
                              void* d_out, int out_size, void* d_ws, size_t ws_size,
                              hipStream_t stream) {
    const float* inp = (const float*)d_in[0];   // [256][1152][8]
    const float* W   = (const float*)d_in[1];   // [1152][10][16][8]
    float* vout = (float*)d_out;                // [256][10][16]

    float* blog = (float*)d_ws;                 // [1152][10]
    float* c    = blog + IC * OC;               // [1152][10]

    hipMemsetAsync(blog, 0, IC * OC * sizeof(float), stream);

    for (int t = 0; t < 3; ++t) {
        softmax_kernel<<<dim3((IC + 255) / 256), dim3(256), 0, stream>>>(blog, c);
        spass_kernel<<<dim3(OC, NB / S_BB), dim3(512), 0, stream>>>(inp, W, c, vout);
        if (t < 2)   // final-iteration b update is dead code in the reference
            delta_kernel<<<dim3(OC, IC / 32), dim3(256), 0, stream>>>(inp, W, vout, blog);
    }
}